// Round 8
// baseline (1770.079 us; speedup 1.0000x reference)
//
#include <hip/hip_runtime.h>

typedef unsigned short u16;
typedef unsigned int u32;
typedef unsigned long long u64;

#define NB 8
#define NPTS 4096
#define MSEL 2048
#define NCENT (NB*MSEL)
#define KNBR 64
#define FEAT 64
#define FIN 67
#define HH 64
#define FOUT 128
#define CAND_CAP 192

#define KP1 96     // layer-1 K padded to 3x32
#define SA 104     // feat A-buffer row stride (bf16 elems)
#define S2 72      // h1/h2 row stride

typedef __attribute__((ext_vector_type(8))) short short8;
typedef __attribute__((ext_vector_type(4))) float f32x4;
typedef __attribute__((ext_vector_type(2))) float f32x2;

__device__ __forceinline__ float bf2f(u16 u) {
    union { u32 i; float f; } v; v.i = ((u32)u) << 16; return v.f;
}
__device__ __forceinline__ u16 f2bf(float f) {
    union { float f; u32 i; } v; v.f = f;
    u32 x = v.i;
    x += 0x7fffu + ((x >> 16) & 1u);
    return (u16)(x >> 16);
}
__device__ __forceinline__ void splitbf(float a, u16& hi, u16& lo) {
    u16 h = f2bf(a);
    hi = h;
    lo = f2bf(__fsub_rn(a, bf2f(h)));
}

// ---------------------------------------------------------------------------
// DPP wave-64 reductions (verified r7-r13).
// ---------------------------------------------------------------------------
__device__ __forceinline__ int wave_max_i(int v) {
    int u;
    u = __builtin_amdgcn_update_dpp(v, v, 0x111, 0xf, 0xf, false); v = max(v, u);
    u = __builtin_amdgcn_update_dpp(v, v, 0x112, 0xf, 0xf, false); v = max(v, u);
    u = __builtin_amdgcn_update_dpp(v, v, 0x114, 0xf, 0xf, false); v = max(v, u);
    u = __builtin_amdgcn_update_dpp(v, v, 0x118, 0xf, 0xf, false); v = max(v, u);
    u = __builtin_amdgcn_update_dpp(v, v, 0x142, 0xf, 0xf, false); v = max(v, u);
    u = __builtin_amdgcn_update_dpp(v, v, 0x143, 0xf, 0xf, false); v = max(v, u);
    return __builtin_amdgcn_readlane(v, 63);
}
__device__ __forceinline__ int wave_min_i(int v) {
    int u;
    u = __builtin_amdgcn_update_dpp(v, v, 0x111, 0xf, 0xf, false); v = min(v, u);
    u = __builtin_amdgcn_update_dpp(v, v, 0x112, 0xf, 0xf, false); v = min(v, u);
    u = __builtin_amdgcn_update_dpp(v, v, 0x114, 0xf, 0xf, false); v = min(v, u);
    u = __builtin_amdgcn_update_dpp(v, v, 0x118, 0xf, 0xf, false); v = min(v, u);
    u = __builtin_amdgcn_update_dpp(v, v, 0x142, 0xf, 0xf, false); v = min(v, u);
    u = __builtin_amdgcn_update_dpp(v, v, 0x143, 0xf, 0xf, false); v = min(v, u);
    return __builtin_amdgcn_readlane(v, 63);
}

struct Cand { int M, I, xb, yb; };   // trivial POD (union-safe)

struct FpsSh {
    float px[NPTS], py[NPTS], pz[NPTS];
    int hist[MSEL];
    Cand sA[2][4];
    float sZ[2][4];
};
struct ConvSh {
    u16 fAh[64*SA], fAl[64*SA];   // feat, then h2 (stride S2)
    u16 h1h[64*S2], h1l[64*S2];
    float cdv[CAND_CAP];
    int   cixv[CAND_CAP];
    int   snbr[KNBR];
    int   sc[2];
};
// Pad to 84 KiB: 2x84KB > 160KB LDS/CU => exactly ONE block per CU. fps
// blocks get exclusive CUs; conv at 1 blk/CU has ~3x the consumption
// capacity needed to track fps production. (r5-verified: -270us)
union __align__(16) FusedSh { FpsSh f; ConvSh c; char pad[86016]; };

// ---------------------------------------------------------------------------
// Kernel 1.5: weight pre-transform (verified) + producer-consumer prog reset.
// Stream-ordered BEFORE the fused kernel => prog re-armed on every launch.
// ---------------------------------------------------------------------------
__global__ __launch_bounds__(256) void wcvt_kernel(const float* __restrict__ W1,
        const float* __restrict__ W2, const float* __restrict__ W3,
        u16* __restrict__ w1h, u16* __restrict__ w1l,
        u16* __restrict__ w2h, u16* __restrict__ w2l,
        u16* __restrict__ w3h, u16* __restrict__ w3l,
        u32* __restrict__ prog) {
    int t = blockIdx.x * 256 + threadIdx.x;
    if (t < NB) prog[t] = 0;
    if (t < 64*KP1) {
        int n = t / KP1, k = t % KP1;
        u16 h, l; splitbf((k < FIN) ? W1[(long)k*HH + n] : 0.0f, h, l);
        w1h[t] = h; w1l[t] = l;
    }
    if (t < 64*64) {
        int n = t / 64, k = t % 64;
        u16 h, l; splitbf(W2[(long)k*HH + n], h, l);
        w2h[t] = h; w2l[t] = l;
    }
    if (t < 128*64) {
        int n = t / 64, k = t % 64;
        u16 h, l; splitbf(W3[(long)k*FOUT + n], h, l);
        w3h[t] = h; w3l[t] = l;
    }
}

// ---------------------------------------------------------------------------
// Fused kernel (r7-verified chassis, 1646us): blocks 0..7 = exact FPS
// publishing selections progressively; blocks 8.. = conv (verified body),
// sel-major mapping, gated on prog. r8 delta vs r7 is ONE change:
//   packed-f32 distance block: 8 x f32x2 replaces 16 scalar points.
//   v_pk_mul/add_f32 are per-component IEEE RNE == the scalar __fmul_rn/
//   __fadd_rn sequence; same (dx*dx+dy*dy)+dz*dz assoc; same 0..15 scan
//   order for the strict-> argmax => selection sequence bit-identical.
//   `#pragma clang fp contract(off)` forbids fma contraction (hipcc default
//   is -ffp-contract=fast-honor-pragmas); absmax tripwire 0.015625 guards.
// ---------------------------------------------------------------------------
__global__ __launch_bounds__(256) void fused_kernel(const float* __restrict__ x,
        const float* __restrict__ pos, int* __restrict__ sel,
        u32* __restrict__ prog,
        const u16* __restrict__ w1h, const u16* __restrict__ w1l,
        const u16* __restrict__ w2h, const u16* __restrict__ w2l,
        const u16* __restrict__ w3h, const u16* __restrict__ w3l,
        const float* __restrict__ b1, const float* __restrict__ b2,
        const float* __restrict__ b3, float* __restrict__ xout,
        float* __restrict__ pos_out, float* __restrict__ batch_out) {
    __shared__ FusedSh S;
    const int t = threadIdx.x;

    if (blockIdx.x < NB) {
        // =================== FPS role ===========
        const int b = blockIdx.x;
        const int wid = t >> 6;
        const float* pb = pos + (long)b * NPTS * 3;

        for (int i = t; i < NPTS; i += 256) {
            S.f.px[i] = pb[i*3+0]; S.f.py[i] = pb[i*3+1]; S.f.pz[i] = pb[i*3+2];
        }
        __syncthreads();

        f32x2 rx2[8], ry2[8], rz2[8], md2[8];
        #pragma unroll
        for (int q = 0; q < 8; ++q) {
            int i0 = t + 256*(2*q);
            int i1 = t + 256*(2*q+1);
            rx2[q].x = S.f.px[i0]; rx2[q].y = S.f.px[i1];
            ry2[q].x = S.f.py[i0]; ry2[q].y = S.f.py[i1];
            rz2[q].x = S.f.pz[i0]; rz2[q].y = S.f.pz[i1];
            md2[q].x = __builtin_inff(); md2[q].y = __builtin_inff();
        }

        int cur = 0;
        float cx = S.f.px[0], cy = S.f.py[0], cz = S.f.pz[0];
        for (int s = 0; s < MSEL; ++s) {
            const int p = s & 1;
            if (t == 0) {
                S.f.hist[s] = cur;
                if ((s & 15) == 15) {
                    if (s >= 16)   // release for PREVIOUS batch: drain is free
                        __hip_atomic_store(&prog[b], (u32)(s - 15),
                                           __ATOMIC_RELEASE, __HIP_MEMORY_SCOPE_AGENT);
                    #pragma unroll
                    for (int q = 0; q < 16; ++q) {
                        int ss = s - 15 + q;
                        __hip_atomic_store(&sel[(long)b*MSEL + ss], S.f.hist[ss],
                                           __ATOMIC_RELAXED, __HIP_MEMORY_SCOPE_AGENT);
                    }
                }
            }
            float bv = -1.0f; int bi = 0;
            {
            #pragma clang fp contract(off)
                const f32x2 cx2 = {cx, cx}, cy2 = {cy, cy}, cz2 = {cz, cz};
                #pragma unroll
                for (int q = 0; q < 8; ++q) {
                    f32x2 dx = rx2[q] - cx2;
                    f32x2 dy = ry2[q] - cy2;
                    f32x2 dz = rz2[q] - cz2;
                    f32x2 dd = dx*dx + dy*dy + dz*dz;   // ((x2+y2)+z2), no fma
                    float m0 = fminf(md2[q].x, dd.x);
                    md2[q].x = m0;
                    if (m0 > bv) { bv = m0; bi = t + 256*(2*q); }     // strict >
                    float m1 = fminf(md2[q].y, dd.y);
                    md2[q].y = m1;
                    if (m1 > bv) { bv = m1; bi = t + 256*(2*q+1); }
                }
            }
            const int fb = (int)__float_as_uint(bv);       // bv >= 0 -> int-ordered
            const int Mw = wave_max_i(fb);
            const u64 mk = __ballot(fb == Mw);
            int Iw;
            if (__popcll(mk) == 1) {                       // unique max (common case)
                Iw = __builtin_amdgcn_readlane(bi, (int)__builtin_ctzll(mk));
            } else {                                       // exact ties: min index
                const int cnd = (fb == Mw) ? bi : 0x7fffffff;
                Iw = wave_min_i(cnd);
            }
            if (t == (Iw & 255)) {                         // owner carries coords
                int j = Iw >> 8;
                f32x2 vx = rx2[j>>1], vy = ry2[j>>1], vz = rz2[j>>1];
                bool odd = (j & 1) != 0;
                Cand cc; cc.M = Mw; cc.I = Iw;
                cc.xb = __float_as_int(odd ? vx.y : vx.x);
                cc.yb = __float_as_int(odd ? vy.y : vy.x);
                S.f.sA[p][wid] = cc;
                S.f.sZ[p][wid] = odd ? vz.y : vz.x;
            }
            __syncthreads();
            Cand v0 = S.f.sA[p][0];
            int M = v0.M, I = v0.I;
            float nx = __int_as_float(v0.xb), ny = __int_as_float(v0.yb);
            float nz = S.f.sZ[p][0];
            #pragma unroll
            for (int w2 = 1; w2 < 4; ++w2) {
                Cand vw = S.f.sA[p][w2];
                if (vw.M > M || (vw.M == M && vw.I < I)) {
                    M = vw.M; I = vw.I;
                    nx = __int_as_float(vw.xb); ny = __int_as_float(vw.yb);
                    nz = S.f.sZ[p][w2];
                }
            }
            cur = I; cx = nx; cy = ny; cz = nz;
        }
        __syncthreads();
        if (t == 0)   // final release: covers last batch (vmcnt drain, once)
            __hip_atomic_store(&prog[b], (u32)MSEL,
                               __ATOMIC_RELEASE, __HIP_MEMORY_SCOPE_AGENT);
        for (int g = t; g < MSEL; g += 256) {
            int i = S.f.hist[g];
            int o = b * MSEL + g;
            pos_out[o*3+0] = S.f.px[i]; pos_out[o*3+1] = S.f.py[i];
            pos_out[o*3+2] = S.f.pz[i];
            batch_out[o] = (float)b;
        }
        return;
    }

    // ====================== CONV role (verified body) =====================
    const int cb = blockIdx.x - NB;
    const int b = cb & 7;                  // sel-major mapping (r5-verified)
    const int s = cb >> 3;
    const int c = b * MSEL + s;
    const int lane = t & 63, w = t >> 6;
    const int colc = lane & 15;
    const float* pb = pos + (long)b * NPTS * 3;

    if (t == 0) {
        S.c.sc[0] = 0; S.c.sc[1] = 0;
        const u32 need = (u32)s + 1u;
        while (__hip_atomic_load(&prog[b], __ATOMIC_ACQUIRE,
                                 __HIP_MEMORY_SCOPE_AGENT) < need)
            __builtin_amdgcn_s_sleep(16);
    }
    __syncthreads();
    const int j0 = (int)__hip_atomic_load(&sel[c], __ATOMIC_RELAXED,
                                          __HIP_MEMORY_SCOPE_AGENT);
    const float qx = pb[j0*3+0], qy = pb[j0*3+1], qz = pb[j0*3+2];

    const int nw = w*16 + colc;            // this wave's column (layers 1-2)
    const float bias1 = b1[nw];
    const float bias2 = b2[nw];
    const float bias3[2] = { b3[(2*w+0)*16 + colc], b3[(2*w+1)*16 + colc] };

    // ---- radius gather (bit-exact; verified r4-r13)
    const float R2 = (float)(0.15 * 0.15);
    for (int it = 0; it < NPTS/256; ++it) {
        int i = t + 256*it;
        float dx = __fsub_rn(qx, pb[i*3+0]);
        float dy = __fsub_rn(qy, pb[i*3+1]);
        float dz = __fsub_rn(qz, pb[i*3+2]);
        float d2 = __fadd_rn(__fadd_rn(__fmul_rn(dx,dx), __fmul_rn(dy,dy)),
                             __fmul_rn(dz,dz));
        if (d2 <= R2) {
            int slot = atomicAdd(&S.c.sc[0], 1);
            if (slot < CAND_CAP) { S.c.cdv[slot] = d2; S.c.cixv[slot] = i; }
        }
    }
    __syncthreads();
    int C = S.c.sc[0]; if (C > CAND_CAP) C = CAND_CAP;
    int cnt;
    if (C <= KNBR) {
        for (int e = t; e < C; e += 256) S.c.snbr[e] = S.c.cixv[e];
        cnt = C;
    } else {
        for (int e = t; e < C; e += 256) {
            float de = S.c.cdv[e]; int ie = S.c.cixv[e];
            int rank = 0;
            for (int f = 0; f < C; ++f) {
                float df = S.c.cdv[f]; int jf = S.c.cixv[f];
                rank += (df < de || (df == de && jf < ie)) ? 1 : 0;
            }
            if (rank < KNBR) {
                int slot = atomicAdd(&S.c.sc[1], 1);
                S.c.snbr[slot] = ie;
            }
        }
        cnt = KNBR;
    }
    __syncthreads();

    // ---- stage features (4 threads/row); zero K-pad cols 67..99
    const int kk = t >> 2, sub = t & 3;
    if (kk < cnt) {
        int j = S.c.snbr[kk];
        const float4* xr4 = (const float4*)(x + ((long)b*NPTS + j) * FEAT);
        #pragma unroll
        for (int i = 0; i < 4; ++i) {
            int ci = sub*4 + i;
            float4 v = xr4[ci];
            u16 h0,l0,h1_,l1_,h2_,l2_,h3_,l3_;
            splitbf(v.x, h0, l0); splitbf(v.y, h1_, l1_);
            splitbf(v.z, h2_, l2_); splitbf(v.w, h3_, l3_);
            int o = kk*SA + ci*4;
            S.c.fAh[o+0]=h0; S.c.fAh[o+1]=h1_; S.c.fAh[o+2]=h2_; S.c.fAh[o+3]=h3_;
            S.c.fAl[o+0]=l0; S.c.fAl[o+1]=l1_; S.c.fAl[o+2]=l2_; S.c.fAl[o+3]=l3_;
        }
        if (sub < 3) {
            float qv = (sub == 0) ? qx : ((sub == 1) ? qy : qz);
            u16 h, l; splitbf(__fsub_rn(pb[j*3+sub], qv), h, l);
            S.c.fAh[kk*SA + 64 + sub] = h; S.c.fAl[kk*SA + 64 + sub] = l;
        } else {
            S.c.fAh[kk*SA + 67] = 0; S.c.fAl[kk*SA + 67] = 0;
        }
        u32* zh = (u32*)&S.c.fAh[kk*SA + 68];
        u32* zl = (u32*)&S.c.fAl[kk*SA + 68];
        #pragma unroll
        for (int i2 = 0; i2 < 4; ++i2) { zh[sub + 4*i2] = 0; zl[sub + 4*i2] = 0; }
    }
    __syncthreads();   // layer 1 reads ALL rows -> full barrier

    const int mL = lane & 15;              // A-row within a 16-row tile
    const int kq = (lane >> 4) * 8;
    const int rgrp = (lane >> 4) * 4;

    // ---- B-fragment loads: this wave's column stripe only (18 KB/wave)
    short8 B1h[3], B1l[3], B2h[2], B2l[2], B3h[2][2], B3l[2][2];
    #pragma unroll
    for (int i = 0; i < 3; ++i) {
        B1h[i] = *(const short8*)&w1h[nw*KP1 + i*32 + kq];
        B1l[i] = *(const short8*)&w1l[nw*KP1 + i*32 + kq];
    }
    #pragma unroll
    for (int i = 0; i < 2; ++i) {
        B2h[i] = *(const short8*)&w2h[nw*64 + i*32 + kq];
        B2l[i] = *(const short8*)&w2l[nw*64 + i*32 + kq];
    }

    // ---- layer 1: 96(67) -> 64, all 4 row-tiles, cols nw
    #pragma unroll
    for (int rt = 0; rt < 4; ++rt) {
        short8 ah[3], al[3];
        #pragma unroll
        for (int i = 0; i < 3; ++i) {
            ah[i] = *(const short8*)&S.c.fAh[(rt*16 + mL)*SA + i*32 + kq];
            al[i] = *(const short8*)&S.c.fAl[(rt*16 + mL)*SA + i*32 + kq];
        }
        f32x4 acc = {bias1, bias1, bias1, bias1};
        #pragma unroll
        for (int i = 0; i < 3; ++i)
            acc = __builtin_amdgcn_mfma_f32_16x16x32_bf16(ah[i], B1h[i], acc, 0,0,0);
        #pragma unroll
        for (int i = 0; i < 3; ++i)
            acc = __builtin_amdgcn_mfma_f32_16x16x32_bf16(ah[i], B1l[i], acc, 0,0,0);
        #pragma unroll
        for (int i = 0; i < 3; ++i)
            acc = __builtin_amdgcn_mfma_f32_16x16x32_bf16(al[i], B1h[i], acc, 0,0,0);
        #pragma unroll
        for (int r = 0; r < 4; ++r) {
            u16 h, l; splitbf(fmaxf(acc[r], 0.0f), h, l);
            int mr = rt*16 + rgrp + r;
            S.c.h1h[mr*S2 + nw] = h; S.c.h1l[mr*S2 + nw] = l;
        }
    }
    // prefetch layer-3 B while layer-1 results drain
    #pragma unroll
    for (int j = 0; j < 2; ++j) {
        int n3 = (2*w + j)*16 + colc;
        #pragma unroll
        for (int i = 0; i < 2; ++i) {
            B3h[j][i] = *(const short8*)&w3h[n3*64 + i*32 + kq];
            B3l[j][i] = *(const short8*)&w3l[n3*64 + i*32 + kq];
        }
    }
    __syncthreads();

    // ---- layer 2: 64 -> 64 (h2 overwrites fA, stride S2)
    #pragma unroll
    for (int rt = 0; rt < 4; ++rt) {
        short8 ah[2], al[2];
        #pragma unroll
        for (int i = 0; i < 2; ++i) {
            ah[i] = *(const short8*)&S.c.h1h[(rt*16 + mL)*S2 + i*32 + kq];
            al[i] = *(const short8*)&S.c.h1l[(rt*16 + mL)*S2 + i*32 + kq];
        }
        f32x4 acc = {bias2, bias2, bias2, bias2};
        #pragma unroll
        for (int i = 0; i < 2; ++i)
            acc = __builtin_amdgcn_mfma_f32_16x16x32_bf16(ah[i], B2h[i], acc, 0,0,0);
        #pragma unroll
        for (int i = 0; i < 2; ++i)
            acc = __builtin_amdgcn_mfma_f32_16x16x32_bf16(ah[i], B2l[i], acc, 0,0,0);
        #pragma unroll
        for (int i = 0; i < 2; ++i)
            acc = __builtin_amdgcn_mfma_f32_16x16x32_bf16(al[i], B2h[i], acc, 0,0,0);
        #pragma unroll
        for (int r = 0; r < 4; ++r) {
            u16 h, l; splitbf(fmaxf(acc[r], 0.0f), h, l);
            int mr = rt*16 + rgrp + r;
            S.c.fAh[mr*S2 + nw] = h; S.c.fAl[mr*S2 + nw] = l;
        }
    }
    __syncthreads();

    // ---- layer 3: 64 -> 128, 2 col stripes/wave, fused relu + masked pool
    #pragma unroll
    for (int j = 0; j < 2; ++j) {
        const float bb = bias3[j];
        float v = 0.0f;   // relu >= 0 and cnt >= 1 -> 0 is identity
        #pragma unroll
        for (int rt = 0; rt < 4; ++rt) {
            short8 ah[2], al[2];
            #pragma unroll
            for (int i = 0; i < 2; ++i) {
                ah[i] = *(const short8*)&S.c.fAh[(rt*16 + mL)*S2 + i*32 + kq];
                al[i] = *(const short8*)&S.c.fAl[(rt*16 + mL)*S2 + i*32 + kq];
            }
            f32x4 acc = {bb, bb, bb, bb};
            #pragma unroll
            for (int i = 0; i < 2; ++i)
                acc = __builtin_amdgcn_mfma_f32_16x16x32_bf16(ah[i], B3h[j][i], acc, 0,0,0);
            #pragma unroll
            for (int i = 0; i < 2; ++i)
                acc = __builtin_amdgcn_mfma_f32_16x16x32_bf16(ah[i], B3l[j][i], acc, 0,0,0);
            #pragma unroll
            for (int i = 0; i < 2; ++i)
                acc = __builtin_amdgcn_mfma_f32_16x16x32_bf16(al[i], B3h[j][i], acc, 0,0,0);
            #pragma unroll
            for (int r = 0; r < 4; ++r) {
                int m = rt*16 + rgrp + r;
                float hv = fmaxf(acc[r], 0.0f);
                v = (m < cnt) ? fmaxf(v, hv) : v;
            }
        }
        v = fmaxf(v, __shfl_xor(v, 16, 64));
        v = fmaxf(v, __shfl_xor(v, 32, 64));
        if (lane < 16)
            xout[(long)c*FOUT + (2*w + j)*16 + lane] = v;
    }
}

// ---------------------------------------------------------------------------
extern "C" void kernel_launch(void* const* d_in, const int* in_sizes, int n_in,
                              void* d_out, int out_size, void* d_ws, size_t ws_size,
                              hipStream_t stream) {
    const float* x   = (const float*)d_in[0];
    const float* pos = (const float*)d_in[1];
    const float* W1 = (const float*)d_in[3];
    const float* b1 = (const float*)d_in[4];
    const float* W2 = (const float*)d_in[5];
    const float* b2 = (const float*)d_in[6];
    const float* W3 = (const float*)d_in[7];
    const float* b3 = (const float*)d_in[8];

    float* out       = (float*)d_out;
    float* xout      = out;
    float* pos_out   = out + (long)NCENT * FOUT;
    float* batch_out = pos_out + (long)NCENT * 3;

    int* sel = (int*)d_ws;
    u16* w1h = (u16*)((char*)d_ws + 65536);
    u16* w1l = w1h + 64*KP1;
    u16* w2h = w1l + 64*KP1;
    u16* w2l = w2h + 64*64;
    u16* w3h = w2l + 64*64;
    u16* w3l = w3h + 128*64;
    u32* prog = (u32*)(w3l + 128*64);

    wcvt_kernel<<<32, 256, 0, stream>>>(W1, W2, W3, w1h, w1l, w2h, w2l,
                                        w3h, w3l, prog);
    fused_kernel<<<NB + NCENT, 256, 0, stream>>>(x, pos, sel, prog,
                                                 w1h, w1l, w2h, w2l, w3h, w3l,
                                                 b1, b2, b3, xout, pos_out,
                                                 batch_out);
}

// Round 9
// 1676.166 us; speedup vs baseline: 1.0560x; 1.0560x over previous
//
#include <hip/hip_runtime.h>

typedef unsigned short u16;
typedef unsigned int u32;
typedef unsigned long long u64;

#define NB 8
#define NPTS 4096
#define MSEL 2048
#define NCENT (NB*MSEL)
#define KNBR 64
#define FEAT 64
#define FIN 67
#define HH 64
#define FOUT 128
#define CAND_CAP 192

#define KP1 96     // layer-1 K padded to 3x32
#define SA 104     // feat A-buffer row stride (bf16 elems)
#define S2 72      // h1/h2 row stride

typedef __attribute__((ext_vector_type(8))) short short8;
typedef __attribute__((ext_vector_type(4))) float f32x4;

__device__ __forceinline__ float bf2f(u16 u) {
    union { u32 i; float f; } v; v.i = ((u32)u) << 16; return v.f;
}
__device__ __forceinline__ u16 f2bf(float f) {
    union { float f; u32 i; } v; v.f = f;
    u32 x = v.i;
    x += 0x7fffu + ((x >> 16) & 1u);
    return (u16)(x >> 16);
}
__device__ __forceinline__ void splitbf(float a, u16& hi, u16& lo) {
    u16 h = f2bf(a);
    hi = h;
    lo = f2bf(__fsub_rn(a, bf2f(h)));
}

// ---------------------------------------------------------------------------
// DPP wave-64 reductions (verified r7-r13).
// ---------------------------------------------------------------------------
__device__ __forceinline__ int wave_max_i(int v) {
    int u;
    u = __builtin_amdgcn_update_dpp(v, v, 0x111, 0xf, 0xf, false); v = max(v, u);
    u = __builtin_amdgcn_update_dpp(v, v, 0x112, 0xf, 0xf, false); v = max(v, u);
    u = __builtin_amdgcn_update_dpp(v, v, 0x114, 0xf, 0xf, false); v = max(v, u);
    u = __builtin_amdgcn_update_dpp(v, v, 0x118, 0xf, 0xf, false); v = max(v, u);
    u = __builtin_amdgcn_update_dpp(v, v, 0x142, 0xf, 0xf, false); v = max(v, u);
    u = __builtin_amdgcn_update_dpp(v, v, 0x143, 0xf, 0xf, false); v = max(v, u);
    return __builtin_amdgcn_readlane(v, 63);
}
__device__ __forceinline__ int wave_min_i(int v) {
    int u;
    u = __builtin_amdgcn_update_dpp(v, v, 0x111, 0xf, 0xf, false); v = min(v, u);
    u = __builtin_amdgcn_update_dpp(v, v, 0x112, 0xf, 0xf, false); v = min(v, u);
    u = __builtin_amdgcn_update_dpp(v, v, 0x114, 0xf, 0xf, false); v = min(v, u);
    u = __builtin_amdgcn_update_dpp(v, v, 0x118, 0xf, 0xf, false); v = min(v, u);
    u = __builtin_amdgcn_update_dpp(v, v, 0x142, 0xf, 0xf, false); v = min(v, u);
    u = __builtin_amdgcn_update_dpp(v, v, 0x143, 0xf, 0xf, false); v = min(v, u);
    return __builtin_amdgcn_readlane(v, 63);
}

struct Cand { int M, I, xb, yb; };   // trivial POD (union-safe)

struct FpsSh {
    float px[NPTS], py[NPTS], pz[NPTS];
    int hist[MSEL];
    Cand sA[2][4];
    float sZ[2][4];
};
struct ConvSh {
    u16 fAh[64*SA], fAl[64*SA];   // feat, then h2 (stride S2)
    u16 h1h[64*S2], h1l[64*S2];
    float cdv[CAND_CAP];
    int   cixv[CAND_CAP];
    int   snbr[KNBR];
    int   sc[2];
};
// Pad to 84 KiB: 2x84KB > 160KB LDS/CU => exactly ONE block per CU. fps
// blocks get exclusive CUs; conv at 1 blk/CU has ~3x the consumption
// capacity needed to track fps production. (r5-verified: -270us)
union __align__(16) FusedSh { FpsSh f; ConvSh c; char pad[86016]; };

// ---------------------------------------------------------------------------
// Kernel 1.5: weight pre-transform (verified) + producer-consumer prog reset.
// Stream-ordered BEFORE the fused kernel => prog re-armed on every launch.
// ---------------------------------------------------------------------------
__global__ __launch_bounds__(256) void wcvt_kernel(const float* __restrict__ W1,
        const float* __restrict__ W2, const float* __restrict__ W3,
        u16* __restrict__ w1h, u16* __restrict__ w1l,
        u16* __restrict__ w2h, u16* __restrict__ w2l,
        u16* __restrict__ w3h, u16* __restrict__ w3l,
        u32* __restrict__ prog) {
    int t = blockIdx.x * 256 + threadIdx.x;
    if (t < NB) prog[t] = 0;
    if (t < 64*KP1) {
        int n = t / KP1, k = t % KP1;
        u16 h, l; splitbf((k < FIN) ? W1[(long)k*HH + n] : 0.0f, h, l);
        w1h[t] = h; w1l[t] = l;
    }
    if (t < 64*64) {
        int n = t / 64, k = t % 64;
        u16 h, l; splitbf(W2[(long)k*HH + n], h, l);
        w2h[t] = h; w2l[t] = l;
    }
    if (t < 128*64) {
        int n = t / 64, k = t % 64;
        u16 h, l; splitbf(W3[(long)k*FOUT + n], h, l);
        w3h[t] = h; w3l[t] = l;
    }
}

// ---------------------------------------------------------------------------
// Fused kernel (r7-verified, 1646us fused / 1679us total — session best):
// blocks 0..7 = exact FPS (r13-verbatim distance+argmax loop) publishing
// selections progressively; blocks 8.. = conv (verified body), sel-major
// mapping, gated on prog. Techniques, each isolated-verified:
//   - producer-consumer fusion, lagged-release handshake (r4/r5)
//   - sel-major conv mapping + 84KB LDS pad -> 1 block/CU (r5, -270us)
//   - ballot fast-path for the argmax index pass (r7, -50us)
// r6 (tree argmax + asm barrier) and r8 (packed f32) both REGRESSED via
// lost ILP/scheduling: do NOT reshape the distance+argmax loop at source
// level. Selection sequence bit-identical; absmax tripwire 0.015625.
// ---------------------------------------------------------------------------
__global__ __launch_bounds__(256) void fused_kernel(const float* __restrict__ x,
        const float* __restrict__ pos, int* __restrict__ sel,
        u32* __restrict__ prog,
        const u16* __restrict__ w1h, const u16* __restrict__ w1l,
        const u16* __restrict__ w2h, const u16* __restrict__ w2l,
        const u16* __restrict__ w3h, const u16* __restrict__ w3l,
        const float* __restrict__ b1, const float* __restrict__ b2,
        const float* __restrict__ b3, float* __restrict__ xout,
        float* __restrict__ pos_out, float* __restrict__ batch_out) {
    __shared__ FusedSh S;
    const int t = threadIdx.x;

    if (blockIdx.x < NB) {
        // =================== FPS role (r13-verbatim arithmetic) ===========
        const int b = blockIdx.x;
        const int wid = t >> 6;
        const float* pb = pos + (long)b * NPTS * 3;

        for (int i = t; i < NPTS; i += 256) {
            S.f.px[i] = pb[i*3+0]; S.f.py[i] = pb[i*3+1]; S.f.pz[i] = pb[i*3+2];
        }
        __syncthreads();

        float rx[16], ry[16], rz[16], md[16];
        #pragma unroll
        for (int j = 0; j < 16; ++j) {
            int i = t + 256*j;
            rx[j] = S.f.px[i]; ry[j] = S.f.py[i]; rz[j] = S.f.pz[i];
            md[j] = __builtin_inff();
        }

        int cur = 0;
        float cx = S.f.px[0], cy = S.f.py[0], cz = S.f.pz[0];
        for (int s = 0; s < MSEL; ++s) {
            const int p = s & 1;
            if (t == 0) {
                S.f.hist[s] = cur;
                if ((s & 15) == 15) {
                    if (s >= 16)   // release for PREVIOUS batch: drain is free
                        __hip_atomic_store(&prog[b], (u32)(s - 15),
                                           __ATOMIC_RELEASE, __HIP_MEMORY_SCOPE_AGENT);
                    #pragma unroll
                    for (int q = 0; q < 16; ++q) {
                        int ss = s - 15 + q;
                        __hip_atomic_store(&sel[(long)b*MSEL + ss], S.f.hist[ss],
                                           __ATOMIC_RELAXED, __HIP_MEMORY_SCOPE_AGENT);
                    }
                }
            }
            float bv = -1.0f; int bi = 0;
            #pragma unroll
            for (int j = 0; j < 16; ++j) {
                float dx = __fsub_rn(rx[j], cx);
                float dy = __fsub_rn(ry[j], cy);
                float dz = __fsub_rn(rz[j], cz);
                float d  = __fadd_rn(__fadd_rn(__fmul_rn(dx,dx), __fmul_rn(dy,dy)),
                                     __fmul_rn(dz,dz));
                float m = fminf(md[j], d);
                md[j] = m;
                if (m > bv) { bv = m; bi = t + 256*j; }   // strict >: first occurrence
            }
            const int fb = (int)__float_as_uint(bv);       // bv >= 0 -> int-ordered
            const int Mw = wave_max_i(fb);
            const u64 mk = __ballot(fb == Mw);
            int Iw;
            if (__popcll(mk) == 1) {                       // unique max (common case)
                Iw = __builtin_amdgcn_readlane(bi, (int)__builtin_ctzll(mk));
            } else {                                       // exact ties: min index
                const int cnd = (fb == Mw) ? bi : 0x7fffffff;
                Iw = wave_min_i(cnd);
            }
            if (t == (Iw & 255)) {                         // owner carries coords
                int j = Iw >> 8;
                Cand cc; cc.M = Mw; cc.I = Iw;
                cc.xb = __float_as_int(rx[j]); cc.yb = __float_as_int(ry[j]);
                S.f.sA[p][wid] = cc;
                S.f.sZ[p][wid] = rz[j];
            }
            __syncthreads();
            Cand v0 = S.f.sA[p][0];
            int M = v0.M, I = v0.I;
            float nx = __int_as_float(v0.xb), ny = __int_as_float(v0.yb);
            float nz = S.f.sZ[p][0];
            #pragma unroll
            for (int w2 = 1; w2 < 4; ++w2) {
                Cand vw = S.f.sA[p][w2];
                if (vw.M > M || (vw.M == M && vw.I < I)) {
                    M = vw.M; I = vw.I;
                    nx = __int_as_float(vw.xb); ny = __int_as_float(vw.yb);
                    nz = S.f.sZ[p][w2];
                }
            }
            cur = I; cx = nx; cy = ny; cz = nz;
        }
        __syncthreads();
        if (t == 0)   // final release: covers last batch (vmcnt drain, once)
            __hip_atomic_store(&prog[b], (u32)MSEL,
                               __ATOMIC_RELEASE, __HIP_MEMORY_SCOPE_AGENT);
        for (int g = t; g < MSEL; g += 256) {
            int i = S.f.hist[g];
            int o = b * MSEL + g;
            pos_out[o*3+0] = S.f.px[i]; pos_out[o*3+1] = S.f.py[i];
            pos_out[o*3+2] = S.f.pz[i];
            batch_out[o] = (float)b;
        }
        return;
    }

    // ====================== CONV role (verified body) =====================
    const int cb = blockIdx.x - NB;
    const int b = cb & 7;                  // sel-major mapping (r5-verified)
    const int s = cb >> 3;
    const int c = b * MSEL + s;
    const int lane = t & 63, w = t >> 6;
    const int colc = lane & 15;
    const float* pb = pos + (long)b * NPTS * 3;

    if (t == 0) {
        S.c.sc[0] = 0; S.c.sc[1] = 0;
        const u32 need = (u32)s + 1u;
        while (__hip_atomic_load(&prog[b], __ATOMIC_ACQUIRE,
                                 __HIP_MEMORY_SCOPE_AGENT) < need)
            __builtin_amdgcn_s_sleep(16);
    }
    __syncthreads();
    const int j0 = (int)__hip_atomic_load(&sel[c], __ATOMIC_RELAXED,
                                          __HIP_MEMORY_SCOPE_AGENT);
    const float qx = pb[j0*3+0], qy = pb[j0*3+1], qz = pb[j0*3+2];

    const int nw = w*16 + colc;            // this wave's column (layers 1-2)
    const float bias1 = b1[nw];
    const float bias2 = b2[nw];
    const float bias3[2] = { b3[(2*w+0)*16 + colc], b3[(2*w+1)*16 + colc] };

    // ---- radius gather (bit-exact; verified r4-r13)
    const float R2 = (float)(0.15 * 0.15);
    for (int it = 0; it < NPTS/256; ++it) {
        int i = t + 256*it;
        float dx = __fsub_rn(qx, pb[i*3+0]);
        float dy = __fsub_rn(qy, pb[i*3+1]);
        float dz = __fsub_rn(qz, pb[i*3+2]);
        float d2 = __fadd_rn(__fadd_rn(__fmul_rn(dx,dx), __fmul_rn(dy,dy)),
                             __fmul_rn(dz,dz));
        if (d2 <= R2) {
            int slot = atomicAdd(&S.c.sc[0], 1);
            if (slot < CAND_CAP) { S.c.cdv[slot] = d2; S.c.cixv[slot] = i; }
        }
    }
    __syncthreads();
    int C = S.c.sc[0]; if (C > CAND_CAP) C = CAND_CAP;
    int cnt;
    if (C <= KNBR) {
        for (int e = t; e < C; e += 256) S.c.snbr[e] = S.c.cixv[e];
        cnt = C;
    } else {
        for (int e = t; e < C; e += 256) {
            float de = S.c.cdv[e]; int ie = S.c.cixv[e];
            int rank = 0;
            for (int f = 0; f < C; ++f) {
                float df = S.c.cdv[f]; int jf = S.c.cixv[f];
                rank += (df < de || (df == de && jf < ie)) ? 1 : 0;
            }
            if (rank < KNBR) {
                int slot = atomicAdd(&S.c.sc[1], 1);
                S.c.snbr[slot] = ie;
            }
        }
        cnt = KNBR;
    }
    __syncthreads();

    // ---- stage features (4 threads/row); zero K-pad cols 67..99
    const int kk = t >> 2, sub = t & 3;
    if (kk < cnt) {
        int j = S.c.snbr[kk];
        const float4* xr4 = (const float4*)(x + ((long)b*NPTS + j) * FEAT);
        #pragma unroll
        for (int i = 0; i < 4; ++i) {
            int ci = sub*4 + i;
            float4 v = xr4[ci];
            u16 h0,l0,h1_,l1_,h2_,l2_,h3_,l3_;
            splitbf(v.x, h0, l0); splitbf(v.y, h1_, l1_);
            splitbf(v.z, h2_, l2_); splitbf(v.w, h3_, l3_);
            int o = kk*SA + ci*4;
            S.c.fAh[o+0]=h0; S.c.fAh[o+1]=h1_; S.c.fAh[o+2]=h2_; S.c.fAh[o+3]=h3_;
            S.c.fAl[o+0]=l0; S.c.fAl[o+1]=l1_; S.c.fAl[o+2]=l2_; S.c.fAl[o+3]=l3_;
        }
        if (sub < 3) {
            float qv = (sub == 0) ? qx : ((sub == 1) ? qy : qz);
            u16 h, l; splitbf(__fsub_rn(pb[j*3+sub], qv), h, l);
            S.c.fAh[kk*SA + 64 + sub] = h; S.c.fAl[kk*SA + 64 + sub] = l;
        } else {
            S.c.fAh[kk*SA + 67] = 0; S.c.fAl[kk*SA + 67] = 0;
        }
        u32* zh = (u32*)&S.c.fAh[kk*SA + 68];
        u32* zl = (u32*)&S.c.fAl[kk*SA + 68];
        #pragma unroll
        for (int i2 = 0; i2 < 4; ++i2) { zh[sub + 4*i2] = 0; zl[sub + 4*i2] = 0; }
    }
    __syncthreads();   // layer 1 reads ALL rows -> full barrier

    const int mL = lane & 15;              // A-row within a 16-row tile
    const int kq = (lane >> 4) * 8;
    const int rgrp = (lane >> 4) * 4;

    // ---- B-fragment loads: this wave's column stripe only (18 KB/wave)
    short8 B1h[3], B1l[3], B2h[2], B2l[2], B3h[2][2], B3l[2][2];
    #pragma unroll
    for (int i = 0; i < 3; ++i) {
        B1h[i] = *(const short8*)&w1h[nw*KP1 + i*32 + kq];
        B1l[i] = *(const short8*)&w1l[nw*KP1 + i*32 + kq];
    }
    #pragma unroll
    for (int i = 0; i < 2; ++i) {
        B2h[i] = *(const short8*)&w2h[nw*64 + i*32 + kq];
        B2l[i] = *(const short8*)&w2l[nw*64 + i*32 + kq];
    }

    // ---- layer 1: 96(67) -> 64, all 4 row-tiles, cols nw
    #pragma unroll
    for (int rt = 0; rt < 4; ++rt) {
        short8 ah[3], al[3];
        #pragma unroll
        for (int i = 0; i < 3; ++i) {
            ah[i] = *(const short8*)&S.c.fAh[(rt*16 + mL)*SA + i*32 + kq];
            al[i] = *(const short8*)&S.c.fAl[(rt*16 + mL)*SA + i*32 + kq];
        }
        f32x4 acc = {bias1, bias1, bias1, bias1};
        #pragma unroll
        for (int i = 0; i < 3; ++i)
            acc = __builtin_amdgcn_mfma_f32_16x16x32_bf16(ah[i], B1h[i], acc, 0,0,0);
        #pragma unroll
        for (int i = 0; i < 3; ++i)
            acc = __builtin_amdgcn_mfma_f32_16x16x32_bf16(ah[i], B1l[i], acc, 0,0,0);
        #pragma unroll
        for (int i = 0; i < 3; ++i)
            acc = __builtin_amdgcn_mfma_f32_16x16x32_bf16(al[i], B1h[i], acc, 0,0,0);
        #pragma unroll
        for (int r = 0; r < 4; ++r) {
            u16 h, l; splitbf(fmaxf(acc[r], 0.0f), h, l);
            int mr = rt*16 + rgrp + r;
            S.c.h1h[mr*S2 + nw] = h; S.c.h1l[mr*S2 + nw] = l;
        }
    }
    // prefetch layer-3 B while layer-1 results drain
    #pragma unroll
    for (int j = 0; j < 2; ++j) {
        int n3 = (2*w + j)*16 + colc;
        #pragma unroll
        for (int i = 0; i < 2; ++i) {
            B3h[j][i] = *(const short8*)&w3h[n3*64 + i*32 + kq];
            B3l[j][i] = *(const short8*)&w3l[n3*64 + i*32 + kq];
        }
    }
    __syncthreads();

    // ---- layer 2: 64 -> 64 (h2 overwrites fA, stride S2)
    #pragma unroll
    for (int rt = 0; rt < 4; ++rt) {
        short8 ah[2], al[2];
        #pragma unroll
        for (int i = 0; i < 2; ++i) {
            ah[i] = *(const short8*)&S.c.h1h[(rt*16 + mL)*S2 + i*32 + kq];
            al[i] = *(const short8*)&S.c.h1l[(rt*16 + mL)*S2 + i*32 + kq];
        }
        f32x4 acc = {bias2, bias2, bias2, bias2};
        #pragma unroll
        for (int i = 0; i < 2; ++i)
            acc = __builtin_amdgcn_mfma_f32_16x16x32_bf16(ah[i], B2h[i], acc, 0,0,0);
        #pragma unroll
        for (int i = 0; i < 2; ++i)
            acc = __builtin_amdgcn_mfma_f32_16x16x32_bf16(ah[i], B2l[i], acc, 0,0,0);
        #pragma unroll
        for (int i = 0; i < 2; ++i)
            acc = __builtin_amdgcn_mfma_f32_16x16x32_bf16(al[i], B2h[i], acc, 0,0,0);
        #pragma unroll
        for (int r = 0; r < 4; ++r) {
            u16 h, l; splitbf(fmaxf(acc[r], 0.0f), h, l);
            int mr = rt*16 + rgrp + r;
            S.c.fAh[mr*S2 + nw] = h; S.c.fAl[mr*S2 + nw] = l;
        }
    }
    __syncthreads();

    // ---- layer 3: 64 -> 128, 2 col stripes/wave, fused relu + masked pool
    #pragma unroll
    for (int j = 0; j < 2; ++j) {
        const float bb = bias3[j];
        float v = 0.0f;   // relu >= 0 and cnt >= 1 -> 0 is identity
        #pragma unroll
        for (int rt = 0; rt < 4; ++rt) {
            short8 ah[2], al[2];
            #pragma unroll
            for (int i = 0; i < 2; ++i) {
                ah[i] = *(const short8*)&S.c.fAh[(rt*16 + mL)*S2 + i*32 + kq];
                al[i] = *(const short8*)&S.c.fAl[(rt*16 + mL)*S2 + i*32 + kq];
            }
            f32x4 acc = {bb, bb, bb, bb};
            #pragma unroll
            for (int i = 0; i < 2; ++i)
                acc = __builtin_amdgcn_mfma_f32_16x16x32_bf16(ah[i], B3h[j][i], acc, 0,0,0);
            #pragma unroll
            for (int i = 0; i < 2; ++i)
                acc = __builtin_amdgcn_mfma_f32_16x16x32_bf16(ah[i], B3l[j][i], acc, 0,0,0);
            #pragma unroll
            for (int i = 0; i < 2; ++i)
                acc = __builtin_amdgcn_mfma_f32_16x16x32_bf16(al[i], B3h[j][i], acc, 0,0,0);
            #pragma unroll
            for (int r = 0; r < 4; ++r) {
                int m = rt*16 + rgrp + r;
                float hv = fmaxf(acc[r], 0.0f);
                v = (m < cnt) ? fmaxf(v, hv) : v;
            }
        }
        v = fmaxf(v, __shfl_xor(v, 16, 64));
        v = fmaxf(v, __shfl_xor(v, 32, 64));
        if (lane < 16)
            xout[(long)c*FOUT + (2*w + j)*16 + lane] = v;
    }
}

// ---------------------------------------------------------------------------
extern "C" void kernel_launch(void* const* d_in, const int* in_sizes, int n_in,
                              void* d_out, int out_size, void* d_ws, size_t ws_size,
                              hipStream_t stream) {
    const float* x   = (const float*)d_in[0];
    const float* pos = (const float*)d_in[1];
    const float* W1 = (const float*)d_in[3];
    const float* b1 = (const float*)d_in[4];
    const float* W2 = (const float*)d_in[5];
    const float* b2 = (const float*)d_in[6];
    const float* W3 = (const float*)d_in[7];
    const float* b3 = (const float*)d_in[8];

    float* out       = (float*)d_out;
    float* xout      = out;
    float* pos_out   = out + (long)NCENT * FOUT;
    float* batch_out = pos_out + (long)NCENT * 3;

    int* sel = (int*)d_ws;
    u16* w1h = (u16*)((char*)d_ws + 65536);
    u16* w1l = w1h + 64*KP1;
    u16* w2h = w1l + 64*KP1;
    u16* w2l = w2h + 64*64;
    u16* w3h = w2l + 64*64;
    u16* w3l = w3h + 128*64;
    u32* prog = (u32*)(w3l + 128*64);

    wcvt_kernel<<<32, 256, 0, stream>>>(W1, W2, W3, w1h, w1l, w2h, w2l,
                                        w3h, w3l, prog);
    fused_kernel<<<NB + NCENT, 256, 0, stream>>>(x, pos, sel, prog,
                                                 w1h, w1l, w2h, w2l, w3h, w3l,
                                                 b1, b2, b3, xout, pos_out,
                                                 batch_out);
}